// Round 6
// baseline (176.732 us; speedup 1.0000x reference)
//
#include <hip/hip_runtime.h>
#include <hip/hip_bf16.h>

#define NROWS 8192
#define KD    1024

typedef __attribute__((ext_vector_type(8))) short bf16x8;
typedef __attribute__((ext_vector_type(4))) float f32x4;

__device__ unsigned short g_x1n[(size_t)NROWS * KD];
__device__ unsigned short g_x2n[(size_t)NROWS * KD];

__device__ __forceinline__ unsigned short f2bf(float f) {
    union { float f; unsigned u; } x; x.f = f;
    return (unsigned short)((x.u + 0x7fffu + ((x.u >> 16) & 1u)) >> 16);  // RNE
}

__global__ __launch_bounds__(256) void norm_cast_kernel(const float* __restrict__ x1,
                                                        const float* __restrict__ x2) {
    int row = blockIdx.x;
    const float* src;
    unsigned short* dst;
    if (row < NROWS) { src = x1 + (size_t)row * KD;           dst = g_x1n + (size_t)row * KD; }
    else             { src = x2 + (size_t)(row - NROWS) * KD; dst = g_x2n + (size_t)(row - NROWS) * KD; }

    int t = threadIdx.x;
    float4 v = ((const float4*)src)[t];
    float s = v.x * v.x + v.y * v.y + v.z * v.z + v.w * v.w;
    #pragma unroll
    for (int off = 32; off > 0; off >>= 1) s += __shfl_down(s, off);

    __shared__ float red[4];
    if ((t & 63) == 0) red[t >> 6] = s;
    __syncthreads();
    float tot = red[0] + red[1] + red[2] + red[3];
    float inv = 1.0f / fmaxf(sqrtf(tot), 1e-8f);

    ushort4 o;
    o.x = f2bf(v.x * inv); o.y = f2bf(v.y * inv);
    o.z = f2bf(v.z * inv); o.w = f2bf(v.w * inv);
    ((ushort4*)dst)[t] = o;
}

__device__ __forceinline__ void gload_lds16(const unsigned short* g, unsigned short* l) {
    __builtin_amdgcn_global_load_lds((const __attribute__((address_space(1))) void*)g,
                                     (__attribute__((address_space(3))) void*)l,
                                     16, 0, 0);
}

#define BARX() do { asm volatile("" ::: "memory"); __builtin_amdgcn_s_barrier(); \
                    asm volatile("" ::: "memory"); } while (0)
#define MFMA16(a, b, c) __builtin_amdgcn_mfma_f32_16x16x32_bf16((a), (b), (c), 0, 0, 0)

struct Ctx {
    const unsigned short* srcA;   // advancing: points at NEXT tile's k-col (incl. trow*KD + scol)
    const unsigned short* srcB;
    unsigned short* ldsf;
    int ldst;                     // t*8 (stage dest elem offset within region)
    int aoff0, aoff1, boff0, boff1;
    int wr, wch;
};

// Stage one half-tile (128 rows x 64 k): 2 x global_load_lds(16B) per thread.
// LDS dest LINEAR; global source carries the inverse swizzle (in srcA/srcB).
__device__ __forceinline__ void stage_half2(Ctx& c, bool isA, int hbit, int region) {
    const unsigned short* src = (isA ? c.srcA : c.srcB) + (size_t)hbit * 128 * KD;
    unsigned short* dst = c.ldsf + region * 8192 + c.ldst;
    gload_lds16(src, dst);
    gload_lds16(src + (size_t)64 * KD, dst + 4096);
}

// One K-tile, tile-granular sync: [stage T+1 | 24 ds_reads + 64 MFMA | vmcnt(0); barrier].
// No intra-tile barriers -> waves desync -> LDS pipe overlaps MFMA pipe across waves.
// Race ledger: stages write BUF^1 (last read tile T-1, drained before T-start barrier);
// reads hit BUF (staged tile T-1, vmcnt(0)-drained); 1-deep prefetch latency covered
// by the full tile body (~2500cy >> 900cy HBM).
template<int BUF, bool SN>
__device__ __forceinline__ void tile_body(Ctx& c, f32x4 (&acc)[8][4]) {
    if (SN) {
        stage_half2(c, true,  0, (BUF ^ 1) * 4 + 0);
        stage_half2(c, true,  1, (BUF ^ 1) * 4 + 1);
        stage_half2(c, false, 0, (BUF ^ 1) * 4 + 2);
        stage_half2(c, false, 1, (BUF ^ 1) * 4 + 3);
        c.srcA += 64; c.srcB += 64;
    }
    __builtin_amdgcn_sched_barrier(0);   // pin stage issue at tile top

    const unsigned short* ab = c.ldsf + (BUF * 4 + c.wr) * 8192;
    const unsigned short* bb = c.ldsf + (BUF * 4 + 2 + c.wch) * 8192;

    bf16x8 Aa[8], Ah[8], Bl[4], Bh[4];
    #pragma unroll
    for (int mi = 0; mi < 4; ++mi) {
        Aa[mi * 2 + 0] = *(const bf16x8*)(ab + mi * 1024 + c.aoff0);
        Aa[mi * 2 + 1] = *(const bf16x8*)(ab + mi * 1024 + c.aoff1);
    }
    #pragma unroll
    for (int ni = 0; ni < 2; ++ni) {
        Bl[ni * 2 + 0] = *(const bf16x8*)(bb + ni * 1024 + c.boff0);
        Bl[ni * 2 + 1] = *(const bf16x8*)(bb + ni * 1024 + c.boff1);
    }
    #pragma unroll
    for (int ni = 0; ni < 2; ++ni) {
        Bh[ni * 2 + 0] = *(const bf16x8*)(bb + (ni + 2) * 1024 + c.boff0);
        Bh[ni * 2 + 1] = *(const bf16x8*)(bb + (ni + 2) * 1024 + c.boff1);
    }
    // q0: Aa x Bl
    #pragma unroll
    for (int mi = 0; mi < 4; ++mi)
        #pragma unroll
        for (int ni = 0; ni < 2; ++ni) {
            acc[mi][ni] = MFMA16(Aa[mi * 2 + 0], Bl[ni * 2 + 0], acc[mi][ni]);
            acc[mi][ni] = MFMA16(Aa[mi * 2 + 1], Bl[ni * 2 + 1], acc[mi][ni]);
        }
    // q1: Aa x Bh
    #pragma unroll
    for (int mi = 0; mi < 4; ++mi)
        #pragma unroll
        for (int ni = 0; ni < 2; ++ni) {
            acc[mi][ni + 2] = MFMA16(Aa[mi * 2 + 0], Bh[ni * 2 + 0], acc[mi][ni + 2]);
            acc[mi][ni + 2] = MFMA16(Aa[mi * 2 + 1], Bh[ni * 2 + 1], acc[mi][ni + 2]);
        }
    // read A-hi (Aa dead from here; compiler may hoist if registers allow)
    #pragma unroll
    for (int mi = 0; mi < 4; ++mi) {
        Ah[mi * 2 + 0] = *(const bf16x8*)(ab + (mi + 4) * 1024 + c.aoff0);
        Ah[mi * 2 + 1] = *(const bf16x8*)(ab + (mi + 4) * 1024 + c.aoff1);
    }
    // q2: Ah x Bh
    #pragma unroll
    for (int mi = 0; mi < 4; ++mi)
        #pragma unroll
        for (int ni = 0; ni < 2; ++ni) {
            acc[mi + 4][ni + 2] = MFMA16(Ah[mi * 2 + 0], Bh[ni * 2 + 0], acc[mi + 4][ni + 2]);
            acc[mi + 4][ni + 2] = MFMA16(Ah[mi * 2 + 1], Bh[ni * 2 + 1], acc[mi + 4][ni + 2]);
        }
    // q3: Ah x Bl
    #pragma unroll
    for (int mi = 0; mi < 4; ++mi)
        #pragma unroll
        for (int ni = 0; ni < 2; ++ni) {
            acc[mi + 4][ni] = MFMA16(Ah[mi * 2 + 0], Bl[ni * 2 + 0], acc[mi + 4][ni]);
            acc[mi + 4][ni] = MFMA16(Ah[mi * 2 + 1], Bl[ni * 2 + 1], acc[mi + 4][ni]);
        }

    asm volatile("s_waitcnt vmcnt(0)" ::: "memory");   // stages (issued a full body ago) done
    BARX();                                            // publish tile T+1; close tile T reads
}

// 256x256 tile, BK=64, 8 waves (2M x 4N), tile-granular-barrier schedule.
__global__ __launch_bounds__(512, 2) void gemm8_kernel(float* __restrict__ C) {
    __shared__ unsigned short lds[2][4][8192];   // 128 KiB

    // L2-rectangle XCD mapping (bijective), bn-band pinned per XCD (round 5: FETCH -63%).
    int bid = blockIdx.x;                 // 1024 blocks
    int xcd  = bid & 7;
    int idx  = bid >> 3;
    int rnd  = idx >> 5;
    int j    = idx & 31;
    int rect = rnd * 8 + xcd;
    int bm = (rect >> 2) * 4 + (j >> 3);
    int bn = (rect & 3) * 8 + (j & 7);

    int t = threadIdx.x;
    int lane = t & 63, wid = t >> 6;
    int wr = wid >> 2, wc = wid & 3;
    int r = lane & 15;
    int s0 = (lane >> 4) ^ (r & 7);       // swizzled 16B slot, kk=0
    int s1 = s0 ^ 4;                      // kk=1

    Ctx c;
    {
        int trow = t >> 3;
        int scol = ((t & 7) ^ (trow & 7)) * 8;   // inverse swizzle on global source
        c.srcA = g_x1n + (size_t)bm * 256 * KD + (size_t)trow * KD + scol;
        c.srcB = g_x2n + (size_t)bn * 256 * KD + (size_t)trow * KD + scol;
    }
    c.ldsf = &lds[0][0][0];
    c.ldst = t * 8;
    c.aoff0 = r * 64 + s0 * 8;
    c.aoff1 = r * 64 + s1 * 8;
    c.boff0 = ((wc & 1) * 64 + r) * 64 + s0 * 8;
    c.boff1 = ((wc & 1) * 64 + r) * 64 + s1 * 8;
    c.wr = wr;
    c.wch = wc >> 1;

    f32x4 acc[8][4] = {};

    // Prologue: stage tile 0 into buf0; drain; publish.
    stage_half2(c, true,  0, 0);
    stage_half2(c, true,  1, 1);
    stage_half2(c, false, 0, 2);
    stage_half2(c, false, 1, 3);
    c.srcA += 64; c.srcB += 64;
    asm volatile("s_waitcnt vmcnt(0)" ::: "memory");
    BARX();

    for (int it = 0; it < 7; ++it) {      // tiles 0..13, staging 1..14
        tile_body<0, true>(c, acc);
        tile_body<1, true>(c, acc);
    }
    tile_body<0, true>(c, acc);           // tile 14, stages 15
    tile_body<1, false>(c, acc);          // tile 15

    // Epilogue: C/D layout col = lane&15, row = (lane>>4)*4 + j.
    int cn = lane & 15, rq = (lane >> 4) * 4;
    int rbase = bm * 256 + wr * 128;
    int cbase = bn * 256 + wc * 64;
    #pragma unroll
    for (int mi = 0; mi < 8; ++mi)
        #pragma unroll
        for (int ni = 0; ni < 4; ++ni)
            #pragma unroll
            for (int j2 = 0; j2 < 4; ++j2)
                C[(size_t)(rbase + mi * 16 + rq + j2) * NROWS + cbase + ni * 16 + cn] =
                    acc[mi][ni][j2] * 20.0f;
}

extern "C" void kernel_launch(void* const* d_in, const int* in_sizes, int n_in,
                              void* d_out, int out_size, void* d_ws, size_t ws_size,
                              hipStream_t stream) {
    (void)in_sizes; (void)n_in; (void)d_ws; (void)ws_size; (void)out_size;
    const float* x1 = (const float*)d_in[0];
    const float* x2 = (const float*)d_in[1];
    float* out = (float*)d_out;

    norm_cast_kernel<<<2 * NROWS, 256, 0, stream>>>(x1, x2);
    gemm8_kernel<<<(NROWS / 256) * (NROWS / 256), 512, 0, stream>>>(out);
}